// Round 1
// 240.563 us; speedup vs baseline: 1.1064x; 1.1064x over previous
//
#include <hip/hip_runtime.h>

#define BATCH 512
#define NNODE 200
#define CIN   200
#define HID   128
#define IPY   232   // padded row stride (shorts): 464B rows -> conflict-free ds_read_b128
#define KCH   7     // 7 K-chunks of 32 (cover 224 >= 200)

typedef __attribute__((ext_vector_type(4))) float  f32x4;
typedef __attribute__((ext_vector_type(4))) int    i32x4;
typedef __attribute__((ext_vector_type(8))) short  sh8;
typedef __attribute__((ext_vector_type(4))) short  sh4;
typedef __attribute__((ext_vector_type(8))) __bf16 bf16x8;

__device__ __forceinline__ short f2bf(float x) {
  union { float f; unsigned u; } v; v.f = x;
  unsigned r = v.u + 0x7FFFu + ((v.u >> 16) & 1u);   // RNE
  return (short)(r >> 16);
}
__device__ __forceinline__ f32x4 mfma16(sh8 a, sh8 b, f32x4 c) {
  return __builtin_amdgcn_mfma_f32_16x16x32_bf16(
      __builtin_bit_cast(bf16x8, a), __builtin_bit_cast(bf16x8, b), c, 0, 0, 0);
}
__device__ __forceinline__ f32x4 mfma16i(sh8 a, i32x4 b, f32x4 c) {
  return __builtin_amdgcn_mfma_f32_16x16x32_bf16(
      __builtin_bit_cast(bf16x8, a), __builtin_bit_cast(bf16x8, b), c, 0, 0, 0);
}
// expand 8 adjacency bits -> 4 dwords of packed {bf16(b_even)|bf16(b_odd)<<16}
__device__ __forceinline__ i32x4 expand8(unsigned byte_) {
  i32x4 w;
#pragma unroll
  for (int h = 0; h < 4; ++h) {
    unsigned p = byte_ >> (2 * h);
    unsigned d = ((p & 1u) ? 0x3F80u : 0u) | ((p & 2u) ? 0x3F800000u : 0u);
    w[h] = (int)d;
  }
  return w;
}

// ---------- k_prep: W1 [200][128] f32 -> W1T [128][232] bf16 (zero-padded cols) ----------
// grid 116*256 = 29696 = 128*232 exactly. Coalesced writes; scattered 4B reads (L2-hot W1).
__global__ __launch_bounds__(256) void k_prep(const float* __restrict__ W1,
                                              short* __restrict__ W1T) {
  const int idx = blockIdx.x * 256 + threadIdx.x;
  const int f = idx / IPY, c = idx - f * IPY;
  W1T[idx] = (c < CIN) ? f2bf(W1[(size_t)c * HID + f]) : (short)0;
}

// ---------- k_gin: one block per batch. y, W1T, adj-bits, deg all LDS-resident ----------
__global__ __launch_bounds__(1024) void k_gin(const float* __restrict__ x,
                                              const int* __restrict__ adj,
                                              const short* __restrict__ W1Tg,
                                              const float* __restrict__ b1,
                                              const float* __restrict__ W2,
                                              const float* __restrict__ b2,
                                              const float* __restrict__ eps1p,
                                              const float* __restrict__ eps2p,
                                              float* __restrict__ out) {
  __shared__ short    ls_w1t[HID * IPY];     // 59,392 B
  __shared__ short    ls_y  [HID * IPY];     // 59,392 B
  __shared__ unsigned ls_bits[224 * 8];      //  7,168 B  col bitmasks: bit t of wd = adj[wd*32+t][j]
  __shared__ float    ls_deg[224];           //    896 B  row degrees
  __shared__ float    ls_part[13][2];        //    104 B  per-jtile partial sums

  const int b    = blockIdx.x;
  const int tid  = threadIdx.x;
  const int wave = tid >> 6, lane = tid & 63;
  const int lq   = lane >> 4, lm = lane & 15;
  const float e1 = eps1p[0], e2 = eps2p[0];
  const int* adjb = adj + (size_t)b * NNODE * NNODE;

  // ================= phase 0: ingest adj (coalesced) + stage W1T =================
  if (wave < 4) {
    // column bitmasks: wave w lane L -> column j = w*64+L ; loads coalesced over j
    const int j  = wave * 64 + lane;
    const int jc = min(j, NNODE - 1);                  // clamp keeps loads in-bounds
    unsigned w[8] = {0, 0, 0, 0, 0, 0, 0, 0};
#pragma unroll
    for (int wd = 0; wd < 7; ++wd) {
      const int cnt = (wd < 6) ? 32 : 8;               // rows 0..199 only
      unsigned a = 0;
#pragma unroll
      for (int t = 0; t < 32; ++t)
        if (t < cnt) a |= (unsigned)(adjb[(wd * 32 + t) * NNODE + jc] & 1) << t;
      w[wd] = a;
    }
    if (j < 224) {
      const bool jv = (j < NNODE);
#pragma unroll
      for (int wd = 0; wd < 8; ++wd) ls_bits[j * 8 + wd] = jv ? w[wd] : 0u;
    }
  } else if (wave < 8) {
    // row degrees: deg[i] = sum_j adj[i][j]; contiguous row read + wave reduce
    const int v = wave - 4;
#pragma unroll 2
    for (int r = 0; r < 50; ++r) {
      const int i = v * 50 + r;
      const int* rp = adjb + (size_t)i * NNODE;
      int s = rp[lane] + rp[64 + lane] + rp[128 + lane] + ((lane < 8) ? rp[192 + lane] : 0);
#pragma unroll
      for (int d = 1; d < 64; d <<= 1) s += __shfl_xor(s, d);
      if (lane == 0) ls_deg[i] = (float)s;
    }
  } else {
    // stage W1T (58 KiB = 58 chunks of 1 KiB) into LDS, waves 8..15
#pragma unroll
    for (int it = 0; it < 8; ++it) {
      const int c = (wave - 8) + it * 8;
      if (c < 58)
        *(sh8*)&ls_w1t[c * 512 + lane * 8] = *(const sh8*)(W1Tg + c * 512 + lane * 8);
    }
    // zero pads: ls_y cols 200..223 (NaN-safety vs zero adjacency bits), deg tail
    const int q = tid - 512;                           // [0,512)
    if (q < 384) {
      const int f = q / 3, p = q - f * 3;
      sh8 z = {0, 0, 0, 0, 0, 0, 0, 0};
      *(sh8*)&ls_y[f * IPY + 200 + p * 8] = z;
    } else if (q < 408) {
      ls_deg[200 + q - 384] = 0.f;
    }
  }
  __syncthreads();

  // ================= phase 1: y = x @ W1 -> LDS (bf16, transposed [f][i]) =================
  if (wave < 13) {
    const int mt  = wave;
    const int row = min(mt * 16 + lm, NNODE - 1);
    const float* xr = x + (size_t)b * NNODE * CIN + (size_t)row * CIN;
    sh8 af[KCH];
#pragma unroll
    for (int k = 0; k < KCH; ++k) {
      const int c0 = k * 32 + lq * 8;
      f32x4 p0 = {0.f, 0.f, 0.f, 0.f}, p1 = {0.f, 0.f, 0.f, 0.f};
      if (c0 < CIN) { p0 = *(const f32x4*)(xr + c0); p1 = *(const f32x4*)(xr + c0 + 4); }
      sh8 a;
#pragma unroll
      for (int jj = 0; jj < 4; ++jj) { a[jj] = f2bf(p0[jj]); a[4 + jj] = f2bf(p1[jj]); }
      af[k] = a;
    }
#pragma unroll 2
    for (int ft = 0; ft < 8; ++ft) {
      const int fb = ft * 16;
      const short* wr = &ls_w1t[(fb + lm) * IPY];      // conflict-free b128 (116 words/row)
      f32x4 acc = {0.f, 0.f, 0.f, 0.f};
#pragma unroll
      for (int k = 0; k < KCH; ++k)
        acc = mfma16(af[k], *(const sh8*)(wr + k * 32 + lq * 8), acc);
      sh4 st;                                          // D: n=lm->f, m=lq*4+r->i
#pragma unroll
      for (int r = 0; r < 4; ++r) st[r] = f2bf(acc[r]);
      if (mt * 16 + lq * 4 < NNODE)                    // keep pad cols exactly zero
        *(sh4*)&ls_y[(fb + lm) * IPY + mt * 16 + lq * 4] = st;
    }
  }
  __syncthreads();

  // ================= phase 2: aggregate + MLP2 + pooled sum, all from LDS =================
  if (wave < 13) {
    const int jt = wave;
    const int j  = jt * 16 + lm;
    const bool jok = (j < NNODE);
    const unsigned cd0 = (unsigned)(unsigned short)f2bf(1.f + e1);   // diag, bit==0
    const unsigned cd1 = (unsigned)(unsigned short)f2bf(2.f + e1);   // diag, bit==1
    unsigned bwa[8];
    *(i32x4*)&bwa[0] = *(const i32x4*)&ls_bits[j * 8];
    *(i32x4*)&bwa[4] = *(const i32x4*)&ls_bits[j * 8 + 4];
    i32x4 bfr[KCH];
#pragma unroll
    for (int k = 0; k < KCH; ++k) {
      const unsigned byte_ = (bwa[k] >> (lq * 8)) & 0xFFu;
      i32x4 w = expand8(byte_);
      const int d = j - (k * 32 + lq * 8);             // diag position within this byte
      if (d >= 0 && d < 8) {
        const unsigned val = ((byte_ >> d) & 1u) ? cd1 : cd0;
        const int h2 = d >> 1, sh = (d & 1) * 16;
        w[h2] = (int)(((unsigned)w[h2] & ~(0xFFFFu << sh)) | (val << sh));
      }
      bfr[k] = w;
    }
    float ga = 0.f, gb = 0.f;
#pragma unroll 2
    for (int ft = 0; ft < 8; ++ft) {
      const int fb = ft * 16;
      const short* yr = &ls_y[(fb + lm) * IPY];        // conflict-free b128
      f32x4 acc = {0.f, 0.f, 0.f, 0.f};
#pragma unroll
      for (int k = 0; k < KCH; ++k)
        acc = mfma16i(*(const sh8*)(yr + k * 32 + lq * 8), bfr[k], acc);
      const f32x4 b1v = *(const f32x4*)(b1 + fb + lq * 4);           // f = fb+lq*4+r
      const f32x4 w2a = *(const f32x4*)(W2 + (fb + lq * 4) * 2);
      const f32x4 w2b = *(const f32x4*)(W2 + (fb + lq * 4) * 2 + 4);
#pragma unroll
      for (int r = 0; r < 4; ++r) {
        const float h = fmaxf(acc[r] + b1v[r], 0.f);
        const float wc0 = (r == 0) ? w2a[0] : (r == 1) ? w2a[2] : (r == 2) ? w2b[0] : w2b[2];
        const float wc1 = (r == 0) ? w2a[1] : (r == 1) ? w2a[3] : (r == 2) ? w2b[1] : w2b[3];
        ga += h * wc0;
        gb += h * wc1;
      }
    }
    ga += __shfl_xor(ga, 16); ga += __shfl_xor(ga, 32);   // sum over lq -> full f-sum per j
    gb += __shfl_xor(gb, 16); gb += __shfl_xor(gb, 32);
    const float wj = 1.f + e2 + ls_deg[min(j, NNODE - 1)];
    float t0 = jok ? wj * ga : 0.f;
    float t1 = jok ? wj * gb : 0.f;
#pragma unroll
    for (int d = 1; d < 16; d <<= 1) { t0 += __shfl_xor(t0, d); t1 += __shfl_xor(t1, d); }
    if (lane == 0) { ls_part[jt][0] = t0; ls_part[jt][1] = t1; }
  }
  __syncthreads();

  if (tid < 2) {                                       // out fully overwritten, no atomics
    float s = 0.f;
#pragma unroll
    for (int q = 0; q < 13; ++q) s += ls_part[q][tid];
    out[b * 2 + tid] = b2[tid] + s * (1.f / NNODE);
  }
}

extern "C" void kernel_launch(void* const* d_in, const int* in_sizes, int n_in,
                              void* d_out, int out_size, void* d_ws, size_t ws_size,
                              hipStream_t stream) {
  const float* x    = (const float*)d_in[0];
  const int*   adj  = (const int*)d_in[1];
  const float* W1   = (const float*)d_in[2];
  const float* b1   = (const float*)d_in[3];
  const float* W2   = (const float*)d_in[4];
  const float* b2   = (const float*)d_in[5];
  const float* eps1 = (const float*)d_in[6];
  const float* eps2 = (const float*)d_in[7];
  float* out = (float*)d_out;

  short* W1T = (short*)d_ws;                           // 59,392 B

  k_prep<<<116, 256, 0, stream>>>(W1, W1T);
  k_gin <<<BATCH, 1024, 0, stream>>>(x, adj, W1T, b1, W2, b2, eps1, eps2, out);
}